// Round 2
// 233.002 us; speedup vs baseline: 1.0512x; 1.0512x over previous
//
#include <hip/hip_runtime.h>
#include <hip/hip_fp16.h>

#define EMB 128

// ---------- fused prep: fp32->fp16 item table + start[] boundaries ----------
__global__ __launch_bounds__(256) void prep_kernel(
    const float* __restrict__ src, __half* __restrict__ dst, int n8,
    const int* __restrict__ beh_user, int* __restrict__ start,
    int n_beh, int n_users)
{
    int t = blockIdx.x * 256 + threadIdx.x;
    if (t < n8) {
        const float4* s = (const float4*)src + (size_t)t * 2;
        float4 f0 = s[0];
        float4 f1 = s[1];
        union { __half h[8]; uint4 u; } pk;
        pk.h[0] = __float2half_rn(f0.x); pk.h[1] = __float2half_rn(f0.y);
        pk.h[2] = __float2half_rn(f0.z); pk.h[3] = __float2half_rn(f0.w);
        pk.h[4] = __float2half_rn(f1.x); pk.h[5] = __float2half_rn(f1.y);
        pk.h[6] = __float2half_rn(f1.z); pk.h[7] = __float2half_rn(f1.w);
        ((uint4*)dst)[t] = pk.u;
    }
    if (t < n_beh) {
        int cur  = beh_user[t];
        int prev = (t == 0) ? -1 : beh_user[t - 1];
        if (cur != prev) {
            for (int u = prev + 1; u <= cur; ++u) start[u] = t;
        }
        if (t == n_beh - 1) {
            for (int u = cur + 1; u <= n_users; ++u) start[u] = n_beh;
        }
    }
}

// One wave per user. Quarter-wave row layout: 16 lanes per row, each lane owns
// 8 dims (16 B fp16, dwordx4) -> one gather instr fetches FOUR rows.
// Chunk = 16 behaviors: lane r (0..15 within quarter) cooperatively loads
// beh_item/beh_cnt[j+r] (coalesced), __shfl distributes 4 slots to each
// quarter. Stream loads for chunk j+16 are prefetched during chunk j's FMAs.
// The tail is a single MASKED chunk (idx=0,cnt=0 for t>=e) instead of a
// serial 2-at-a-time loop -> no dependent gather round-trips at the end.
// NOTE: macro parameter must NOT be named `w` — member access `.w` would be
// substituted by the preprocessor.
#define ACCUM(W_, c)                                              \
    {                                                             \
        float2 f01 = __half22float2(*(const __half2*)&(W_).x);    \
        float2 f23 = __half22float2(*(const __half2*)&(W_).y);    \
        float2 f45 = __half22float2(*(const __half2*)&(W_).z);    \
        float2 f67 = __half22float2(*(const __half2*)&(W_).w);    \
        a0 = fmaf(f01.x, (c), a0); a1 = fmaf(f01.y, (c), a1);     \
        a2 = fmaf(f23.x, (c), a2); a3 = fmaf(f23.y, (c), a3);     \
        a4 = fmaf(f45.x, (c), a4); a5 = fmaf(f45.y, (c), a5);     \
        a6 = fmaf(f67.x, (c), a6); a7 = fmaf(f67.y, (c), a7);     \
    }

__global__ __launch_bounds__(256) void per_user_kernel(
    const int*    __restrict__ user_ids,
    const int*    __restrict__ group_ids,
    const int*    __restrict__ beh_item,
    const float*  __restrict__ beh_cnt,
    const float*  __restrict__ user_table,
    const __half* __restrict__ item_f16,
    const int*    __restrict__ start,
    float*        __restrict__ out,
    int n_users)
{
    const int lane = threadIdx.x & 63;
    const int q    = lane >> 4;   // quarter 0..3
    const int r    = lane & 15;   // lane within quarter; owns dims [r*8, r*8+8)
    const int wave = threadIdx.x >> 6;
    const int user = blockIdx.x * 4 + wave;

    __shared__ float lds_acc[EMB];
    __shared__ int   lds_grp[4];
    if (threadIdx.x < EMB) lds_acc[threadIdx.x] = 0.0f;

    float a0 = 0.f, a1 = 0.f, a2 = 0.f, a3 = 0.f;
    float a4 = 0.f, a5 = 0.f, a6 = 0.f, a7 = 0.f;
    int g = -1;

    if (user < n_users) {
        const int s = start[user];
        const int e = start[user + 1];

        const __half* itp = item_f16 + r * 8;   // this lane's 16B slice of any row

        // cooperative stream load for the first chunk
        int   idx_c = 0;
        float cnt_c = 0.f;
        {
            int t0 = s + r;
            if (t0 < e) { idx_c = beh_item[t0]; cnt_c = beh_cnt[t0]; }
        }

        for (int j = s; j < e; j += 16) {
            // prefetch next chunk's stream (coalesced, masked)
            int   idx_n = 0;
            float cnt_n = 0.f;
            int   tn = j + 16 + r;
            if (tn < e) { idx_n = beh_item[tn]; cnt_n = beh_cnt[tn]; }

            // distribute this quarter's 4 slots (all quarters hold identical
            // stream data; width-16 shfl stays within the quarter)
            int   bi0 = __shfl(idx_c, q * 4 + 0, 16);
            int   bi1 = __shfl(idx_c, q * 4 + 1, 16);
            int   bi2 = __shfl(idx_c, q * 4 + 2, 16);
            int   bi3 = __shfl(idx_c, q * 4 + 3, 16);
            float c0  = __shfl(cnt_c, q * 4 + 0, 16);
            float c1  = __shfl(cnt_c, q * 4 + 1, 16);
            float c2  = __shfl(cnt_c, q * 4 + 2, 16);
            float c3  = __shfl(cnt_c, q * 4 + 3, 16);

            // 4 row-gathers in flight per lane (16 rows per wave)
            uint4 w0 = *(const uint4*)(itp + (size_t)bi0 * EMB);
            uint4 w1 = *(const uint4*)(itp + (size_t)bi1 * EMB);
            uint4 w2 = *(const uint4*)(itp + (size_t)bi2 * EMB);
            uint4 w3 = *(const uint4*)(itp + (size_t)bi3 * EMB);

            ACCUM(w0, c0);
            ACCUM(w1, c1);
            ACCUM(w2, c2);
            ACCUM(w3, c3);

            idx_c = idx_n;
            cnt_c = cnt_n;
        }

        // combine the 4 quarters (lanes with equal r hold partials of same dims)
        a0 += __shfl_xor(a0, 16, 64); a1 += __shfl_xor(a1, 16, 64);
        a2 += __shfl_xor(a2, 16, 64); a3 += __shfl_xor(a3, 16, 64);
        a4 += __shfl_xor(a4, 16, 64); a5 += __shfl_xor(a5, 16, 64);
        a6 += __shfl_xor(a6, 16, 64); a7 += __shfl_xor(a7, 16, 64);
        a0 += __shfl_xor(a0, 32, 64); a1 += __shfl_xor(a1, 32, 64);
        a2 += __shfl_xor(a2, 32, 64); a3 += __shfl_xor(a3, 32, 64);
        a4 += __shfl_xor(a4, 32, 64); a5 += __shfl_xor(a5, 32, 64);
        a6 += __shfl_xor(a6, 32, 64); a7 += __shfl_xor(a7, 32, 64);

        const int uid = user_ids[user];
        if (uid != 0) {
            const float* up = user_table + (size_t)uid * EMB + r * 8;
            float4 u0 = *(const float4*)up;
            float4 u1 = *(const float4*)(up + 4);
            a0 *= u0.x; a1 *= u0.y; a2 *= u0.z; a3 *= u0.w;
            a4 *= u1.x; a5 *= u1.y; a6 *= u1.z; a7 *= u1.w;
        } else {
            a0 = a1 = a2 = a3 = a4 = a5 = a6 = a7 = 0.f;
        }

        g = group_ids[user];
    }

    // quarter q writes dims r*8 + 2q, r*8 + 2q + 1 (union over q,r = 128 dims)
    float v0, v1;
    if      (q == 0) { v0 = a0; v1 = a1; }
    else if (q == 1) { v0 = a2; v1 = a3; }
    else if (q == 2) { v0 = a4; v1 = a5; }
    else             { v0 = a6; v1 = a7; }
    const int d0 = r * 8 + q * 2;

    if (lane == 0) lds_grp[wave] = g;
    __syncthreads();

    const int g0 = lds_grp[0];
    const bool same = (g0 >= 0) && (lds_grp[1] == g0) &&
                      (lds_grp[2] == g0) && (lds_grp[3] == g0);
    if (same) {
        atomicAdd(&lds_acc[d0],     v0);
        atomicAdd(&lds_acc[d0 + 1], v1);
        __syncthreads();
        if (threadIdx.x < 64) {
            const int d = threadIdx.x * 2;
            atomicAdd(&out[(size_t)g0 * EMB + d],     lds_acc[d]);
            atomicAdd(&out[(size_t)g0 * EMB + d + 1], lds_acc[d + 1]);
        }
    } else if (g >= 0) {
        atomicAdd(&out[(size_t)g * EMB + d0],     v0);
        atomicAdd(&out[(size_t)g * EMB + d0 + 1], v1);
    }
}

// ---------- fp32 fallback (ws too small for fp16 table) ----------
__global__ __launch_bounds__(256) void per_user_f32_kernel(
    const int*   __restrict__ user_ids,
    const int*   __restrict__ group_ids,
    const int*   __restrict__ beh_item,
    const float* __restrict__ beh_cnt,
    const int*   __restrict__ beh_user,
    const float* __restrict__ user_table,
    const float* __restrict__ item_f32,
    float*       __restrict__ out,
    int n_users, int n_beh)
{
    const int lane = threadIdx.x & 63;
    const int wave = threadIdx.x >> 6;
    const int user = blockIdx.x * 4 + wave;
    float2 acc = make_float2(0.f, 0.f);
    int g = -1;
    if (user < n_users) {
        int lo = 0, hi = n_beh;
        while (lo < hi) { int m = (lo + hi) >> 1; if (beh_user[m] < user) lo = m + 1; else hi = m; }
        int s = lo; hi = n_beh;
        while (lo < hi) { int m = (lo + hi) >> 1; if (beh_user[m] <= user) lo = m + 1; else hi = m; }
        int e = lo;
        for (int j = s; j < e; ++j) {
            int   b = beh_item[j];
            float c = beh_cnt[j];
            float2 v = *(const float2*)(item_f32 + (size_t)b * EMB + lane * 2);
            acc.x = fmaf(v.x, c, acc.x);
            acc.y = fmaf(v.y, c, acc.y);
        }
        int uid = user_ids[user];
        float2 ue = make_float2(0.f, 0.f);
        if (uid != 0) ue = *(const float2*)(user_table + (size_t)uid * EMB + lane * 2);
        acc.x *= ue.x; acc.y *= ue.y;
        g = group_ids[user];
    }
    if (g >= 0) {
        atomicAdd(&out[(size_t)g * EMB + lane * 2],     acc.x);
        atomicAdd(&out[(size_t)g * EMB + lane * 2 + 1], acc.y);
    }
}

extern "C" void kernel_launch(void* const* d_in, const int* in_sizes, int n_in,
                              void* d_out, int out_size, void* d_ws, size_t ws_size,
                              hipStream_t stream) {
    const int*   user_ids   = (const int*)  d_in[0];
    const int*   group_ids  = (const int*)  d_in[1];
    const int*   beh_item   = (const int*)  d_in[2];
    const float* beh_cnt    = (const float*)d_in[3];
    const int*   beh_user   = (const int*)  d_in[4];
    const float* user_table = (const float*)d_in[5];
    const float* item_table = (const float*)d_in[6];

    const int n_users = in_sizes[0];
    const int n_beh   = in_sizes[2];
    const int item_n  = in_sizes[6] / EMB;

    float* out = (float*)d_out;
    (void)hipMemsetAsync(out, 0, (size_t)out_size * sizeof(float), stream);

    // ws layout: start | item_f16 (256B aligned)
    size_t start_bytes = (size_t)(n_users + 1) * sizeof(int);
    size_t f16_off     = (start_bytes + 255) & ~(size_t)255;
    size_t f16_bytes   = (size_t)item_n * EMB * sizeof(__half);

    if (ws_size < f16_off + f16_bytes) {
        int ublocks = (n_users + 3) / 4;
        per_user_f32_kernel<<<ublocks, 256, 0, stream>>>(
            user_ids, group_ids, beh_item, beh_cnt, beh_user,
            user_table, item_table, out, n_users, n_beh);
        return;
    }

    int*    start    = (int*)d_ws;
    __half* item_f16 = (__half*)((char*)d_ws + f16_off);

    int n8 = (item_n * EMB) / 8;
    int prep_n = n8 > n_beh ? n8 : n_beh;
    prep_kernel<<<(prep_n + 255) / 256, 256, 0, stream>>>(
        item_table, item_f16, n8, beh_user, start, n_beh, n_users);

    int ublocks = (n_users + 3) / 4;
    per_user_kernel<<<ublocks, 256, 0, stream>>>(
        user_ids, group_ids, beh_item, beh_cnt,
        user_table, item_f16, start, out, n_users);
}

// Round 3
// 223.677 us; speedup vs baseline: 1.0951x; 1.0417x over previous
//
#include <hip/hip_runtime.h>
#include <hip/hip_fp16.h>

#define EMB 128

// ---------- fused prep: fp32->fp16 item table + start[] boundaries ----------
__global__ __launch_bounds__(256) void prep_kernel(
    const float* __restrict__ src, __half* __restrict__ dst, int n8,
    const int* __restrict__ beh_user, int* __restrict__ start,
    int n_beh, int n_users)
{
    int t = blockIdx.x * 256 + threadIdx.x;
    if (t < n8) {
        const float4* s = (const float4*)src + (size_t)t * 2;
        float4 f0 = s[0];
        float4 f1 = s[1];
        union { __half h[8]; uint4 u; } pk;
        pk.h[0] = __float2half_rn(f0.x); pk.h[1] = __float2half_rn(f0.y);
        pk.h[2] = __float2half_rn(f0.z); pk.h[3] = __float2half_rn(f0.w);
        pk.h[4] = __float2half_rn(f1.x); pk.h[5] = __float2half_rn(f1.y);
        pk.h[6] = __float2half_rn(f1.z); pk.h[7] = __float2half_rn(f1.w);
        ((uint4*)dst)[t] = pk.u;
    }
    if (t < n_beh) {
        int cur  = beh_user[t];
        int prev = (t == 0) ? -1 : beh_user[t - 1];
        if (cur != prev) {
            for (int u = prev + 1; u <= cur; ++u) start[u] = t;
        }
        if (t == n_beh - 1) {
            for (int u = cur + 1; u <= n_users; ++u) start[u] = n_beh;
        }
    }
}

// One wave per user. Quarter-wave row layout: 16 lanes per row, each lane owns
// 8 dims (16 B fp16, dwordx4) -> one gather instr fetches FOUR rows.
//
// 2-deep software pipeline (the R2 loop fully drained vmcnt every chunk):
//   invariant at loop top: gathers for chunk k ISSUED (wc*), stream for
//   chunk k+1 in regs (idxN/cntN), counts for chunk k in regs (cc*).
//   body: (1) stream-prefetch chunk k+2  (2) shfl chunk k+1 slots + issue
//   its 4 gathers  (3) ACCUM chunk k (partial vmcnt wait; k+1 stays in
//   flight)  (4) rotate.
// Once-use streams (beh_item/beh_cnt, user_table rows) use nontemporal
// loads so they don't evict item rows from L2.
// NOTE: macro parameter must NOT be named `w` (preprocessor would rewrite
// the `.w` member access).
#define ACCUM(W_, c)                                              \
    {                                                             \
        float2 f01 = __half22float2(*(const __half2*)&(W_).x);    \
        float2 f23 = __half22float2(*(const __half2*)&(W_).y);    \
        float2 f45 = __half22float2(*(const __half2*)&(W_).z);    \
        float2 f67 = __half22float2(*(const __half2*)&(W_).w);    \
        a0 = fmaf(f01.x, (c), a0); a1 = fmaf(f01.y, (c), a1);     \
        a2 = fmaf(f23.x, (c), a2); a3 = fmaf(f23.y, (c), a3);     \
        a4 = fmaf(f45.x, (c), a4); a5 = fmaf(f45.y, (c), a5);     \
        a6 = fmaf(f67.x, (c), a6); a7 = fmaf(f67.y, (c), a7);     \
    }

__global__ __launch_bounds__(256) void per_user_kernel(
    const int*    __restrict__ user_ids,
    const int*    __restrict__ group_ids,
    const int*    __restrict__ beh_item,
    const float*  __restrict__ beh_cnt,
    const float*  __restrict__ user_table,
    const __half* __restrict__ item_f16,
    const int*    __restrict__ start,
    float*        __restrict__ out,
    int n_users)
{
    const int lane = threadIdx.x & 63;
    const int q    = lane >> 4;   // quarter 0..3
    const int r    = lane & 15;   // lane within quarter; owns dims [r*8, r*8+8)
    const int wave = threadIdx.x >> 6;
    const int user = blockIdx.x * 4 + wave;

    __shared__ float lds_acc[EMB];
    __shared__ int   lds_grp[4];
    if (threadIdx.x < EMB) lds_acc[threadIdx.x] = 0.0f;

    float a0 = 0.f, a1 = 0.f, a2 = 0.f, a3 = 0.f;
    float a4 = 0.f, a5 = 0.f, a6 = 0.f, a7 = 0.f;
    int g = -1;

    if (user < n_users) {
        const int s = start[user];
        const int e = start[user + 1];
        g = group_ids[user];

        if (s < e) {
            const __half* itp = item_f16 + r * 8;  // this lane's 16B slice of any row

            // ---- prologue: stream chunk0 + chunk1, issue chunk0 gathers ----
            int   idx0 = 0; float cnt0 = 0.f;
            {
                int t0 = s + r;
                if (t0 < e) { idx0 = __builtin_nontemporal_load(beh_item + t0);
                              cnt0 = __builtin_nontemporal_load(beh_cnt + t0); }
            }
            int   idxN = 0; float cntN = 0.f;
            {
                int t1 = s + 16 + r;
                if (t1 < e) { idxN = __builtin_nontemporal_load(beh_item + t1);
                              cntN = __builtin_nontemporal_load(beh_cnt + t1); }
            }
            int   bi0 = __shfl(idx0, q * 4 + 0, 16);
            int   bi1 = __shfl(idx0, q * 4 + 1, 16);
            int   bi2 = __shfl(idx0, q * 4 + 2, 16);
            int   bi3 = __shfl(idx0, q * 4 + 3, 16);
            float cc0 = __shfl(cnt0, q * 4 + 0, 16);
            float cc1 = __shfl(cnt0, q * 4 + 1, 16);
            float cc2 = __shfl(cnt0, q * 4 + 2, 16);
            float cc3 = __shfl(cnt0, q * 4 + 3, 16);
            uint4 wc0 = *(const uint4*)(itp + (size_t)bi0 * EMB);
            uint4 wc1 = *(const uint4*)(itp + (size_t)bi1 * EMB);
            uint4 wc2 = *(const uint4*)(itp + (size_t)bi2 * EMB);
            uint4 wc3 = *(const uint4*)(itp + (size_t)bi3 * EMB);

            #pragma unroll 2
            for (int j = s; ; ) {
                // (1) stream prefetch chunk k+2 (masked, nontemporal)
                int   idx2 = 0; float cnt2 = 0.f;
                {
                    int t2 = j + 32 + r;
                    if (t2 < e) { idx2 = __builtin_nontemporal_load(beh_item + t2);
                                  cnt2 = __builtin_nontemporal_load(beh_cnt + t2); }
                }
                // (2) chunk k+1: shfl slots (stream already in regs), issue gathers.
                // Masked-out slots have idx 0 -> row 0, L1-hot and harmless.
                int   ni0 = __shfl(idxN, q * 4 + 0, 16);
                int   ni1 = __shfl(idxN, q * 4 + 1, 16);
                int   ni2 = __shfl(idxN, q * 4 + 2, 16);
                int   ni3 = __shfl(idxN, q * 4 + 3, 16);
                float nc0 = __shfl(cntN, q * 4 + 0, 16);
                float nc1 = __shfl(cntN, q * 4 + 1, 16);
                float nc2 = __shfl(cntN, q * 4 + 2, 16);
                float nc3 = __shfl(cntN, q * 4 + 3, 16);
                uint4 wn0 = *(const uint4*)(itp + (size_t)ni0 * EMB);
                uint4 wn1 = *(const uint4*)(itp + (size_t)ni1 * EMB);
                uint4 wn2 = *(const uint4*)(itp + (size_t)ni2 * EMB);
                uint4 wn3 = *(const uint4*)(itp + (size_t)ni3 * EMB);

                // (3) consume chunk k (waits only its own gathers)
                ACCUM(wc0, cc0);
                ACCUM(wc1, cc1);
                ACCUM(wc2, cc2);
                ACCUM(wc3, cc3);

                j += 16;
                if (j >= e) break;

                // (4) rotate roles
                wc0 = wn0; wc1 = wn1; wc2 = wn2; wc3 = wn3;
                cc0 = nc0; cc1 = nc1; cc2 = nc2; cc3 = nc3;
                idxN = idx2; cntN = cnt2;
            }
        }

        // combine the 4 quarters (lanes with equal r hold partials of same dims)
        a0 += __shfl_xor(a0, 16, 64); a1 += __shfl_xor(a1, 16, 64);
        a2 += __shfl_xor(a2, 16, 64); a3 += __shfl_xor(a3, 16, 64);
        a4 += __shfl_xor(a4, 16, 64); a5 += __shfl_xor(a5, 16, 64);
        a6 += __shfl_xor(a6, 16, 64); a7 += __shfl_xor(a7, 16, 64);
        a0 += __shfl_xor(a0, 32, 64); a1 += __shfl_xor(a1, 32, 64);
        a2 += __shfl_xor(a2, 32, 64); a3 += __shfl_xor(a3, 32, 64);
        a4 += __shfl_xor(a4, 32, 64); a5 += __shfl_xor(a5, 32, 64);
        a6 += __shfl_xor(a6, 32, 64); a7 += __shfl_xor(a7, 32, 64);

        const int uid = user_ids[user];
        if (uid != 0) {
            // once-use row: nontemporal scalar loads (same cache lines, no L2 alloc)
            const float* up = user_table + (size_t)uid * EMB + r * 8;
            a0 *= __builtin_nontemporal_load(up + 0);
            a1 *= __builtin_nontemporal_load(up + 1);
            a2 *= __builtin_nontemporal_load(up + 2);
            a3 *= __builtin_nontemporal_load(up + 3);
            a4 *= __builtin_nontemporal_load(up + 4);
            a5 *= __builtin_nontemporal_load(up + 5);
            a6 *= __builtin_nontemporal_load(up + 6);
            a7 *= __builtin_nontemporal_load(up + 7);
        } else {
            a0 = a1 = a2 = a3 = a4 = a5 = a6 = a7 = 0.f;
        }
    }

    // quarter q writes dims r*8 + 2q, r*8 + 2q + 1 (union over q,r = 128 dims)
    float v0, v1;
    if      (q == 0) { v0 = a0; v1 = a1; }
    else if (q == 1) { v0 = a2; v1 = a3; }
    else if (q == 2) { v0 = a4; v1 = a5; }
    else             { v0 = a6; v1 = a7; }
    const int d0 = r * 8 + q * 2;

    if (lane == 0) lds_grp[wave] = g;
    __syncthreads();

    const int g0 = lds_grp[0];
    const bool same = (g0 >= 0) && (lds_grp[1] == g0) &&
                      (lds_grp[2] == g0) && (lds_grp[3] == g0);
    if (same) {
        atomicAdd(&lds_acc[d0],     v0);
        atomicAdd(&lds_acc[d0 + 1], v1);
        __syncthreads();
        if (threadIdx.x < 64) {
            const int d = threadIdx.x * 2;
            atomicAdd(&out[(size_t)g0 * EMB + d],     lds_acc[d]);
            atomicAdd(&out[(size_t)g0 * EMB + d + 1], lds_acc[d + 1]);
        }
    } else if (g >= 0) {
        atomicAdd(&out[(size_t)g * EMB + d0],     v0);
        atomicAdd(&out[(size_t)g * EMB + d0 + 1], v1);
    }
}

// ---------- fp32 fallback (ws too small for fp16 table) ----------
__global__ __launch_bounds__(256) void per_user_f32_kernel(
    const int*   __restrict__ user_ids,
    const int*   __restrict__ group_ids,
    const int*   __restrict__ beh_item,
    const float* __restrict__ beh_cnt,
    const int*   __restrict__ beh_user,
    const float* __restrict__ user_table,
    const float* __restrict__ item_f32,
    float*       __restrict__ out,
    int n_users, int n_beh)
{
    const int lane = threadIdx.x & 63;
    const int wave = threadIdx.x >> 6;
    const int user = blockIdx.x * 4 + wave;
    float2 acc = make_float2(0.f, 0.f);
    int g = -1;
    if (user < n_users) {
        int lo = 0, hi = n_beh;
        while (lo < hi) { int m = (lo + hi) >> 1; if (beh_user[m] < user) lo = m + 1; else hi = m; }
        int s = lo; hi = n_beh;
        while (lo < hi) { int m = (lo + hi) >> 1; if (beh_user[m] <= user) lo = m + 1; else hi = m; }
        int e = lo;
        for (int j = s; j < e; ++j) {
            int   b = beh_item[j];
            float c = beh_cnt[j];
            float2 v = *(const float2*)(item_f32 + (size_t)b * EMB + lane * 2);
            acc.x = fmaf(v.x, c, acc.x);
            acc.y = fmaf(v.y, c, acc.y);
        }
        int uid = user_ids[user];
        float2 ue = make_float2(0.f, 0.f);
        if (uid != 0) ue = *(const float2*)(user_table + (size_t)uid * EMB + lane * 2);
        acc.x *= ue.x; acc.y *= ue.y;
        g = group_ids[user];
    }
    if (g >= 0) {
        atomicAdd(&out[(size_t)g * EMB + lane * 2],     acc.x);
        atomicAdd(&out[(size_t)g * EMB + lane * 2 + 1], acc.y);
    }
}

extern "C" void kernel_launch(void* const* d_in, const int* in_sizes, int n_in,
                              void* d_out, int out_size, void* d_ws, size_t ws_size,
                              hipStream_t stream) {
    const int*   user_ids   = (const int*)  d_in[0];
    const int*   group_ids  = (const int*)  d_in[1];
    const int*   beh_item   = (const int*)  d_in[2];
    const float* beh_cnt    = (const float*)d_in[3];
    const int*   beh_user   = (const int*)  d_in[4];
    const float* user_table = (const float*)d_in[5];
    const float* item_table = (const float*)d_in[6];

    const int n_users = in_sizes[0];
    const int n_beh   = in_sizes[2];
    const int item_n  = in_sizes[6] / EMB;

    float* out = (float*)d_out;
    (void)hipMemsetAsync(out, 0, (size_t)out_size * sizeof(float), stream);

    // ws layout: start | item_f16 (256B aligned)
    size_t start_bytes = (size_t)(n_users + 1) * sizeof(int);
    size_t f16_off     = (start_bytes + 255) & ~(size_t)255;
    size_t f16_bytes   = (size_t)item_n * EMB * sizeof(__half);

    if (ws_size < f16_off + f16_bytes) {
        int ublocks = (n_users + 3) / 4;
        per_user_f32_kernel<<<ublocks, 256, 0, stream>>>(
            user_ids, group_ids, beh_item, beh_cnt, beh_user,
            user_table, item_table, out, n_users, n_beh);
        return;
    }

    int*    start    = (int*)d_ws;
    __half* item_f16 = (__half*)((char*)d_ws + f16_off);

    int n8 = (item_n * EMB) / 8;
    int prep_n = n8 > n_beh ? n8 : n_beh;
    prep_kernel<<<(prep_n + 255) / 256, 256, 0, stream>>>(
        item_table, item_f16, n8, beh_user, start, n_beh, n_users);

    int ublocks = (n_users + 3) / 4;
    per_user_kernel<<<ublocks, 256, 0, stream>>>(
        user_ids, group_ids, beh_item, beh_cnt,
        user_table, item_f16, start, out, n_users);
}